// Round 14
// baseline (414.052 us; speedup 1.0000x reference)
//
#include <hip/hip_runtime.h>
#include <math.h>

#define NN 32768
#define NE 65536

typedef __attribute__((ext_vector_type(8))) short bf16x8;
typedef __attribute__((ext_vector_type(4))) float f32x4;

__device__ __forceinline__ float elu_f(float v) {
    return v > 0.f ? v : (expf(v) - 1.f);
}
__device__ __forceinline__ unsigned short bf16_rn(float f) {
    unsigned u = __float_as_uint(f);
    return (unsigned short)((u + 0x7FFFu + ((u >> 16) & 1u)) >> 16);
}
__device__ __forceinline__ float bf16_to_f(unsigned short h) {
    return __uint_as_float(((unsigned)h) << 16);
}
// async global->LDS, 16B per lane; LDS dest = uniform base + lane*16 (HW)
__device__ __forceinline__ void gld16(const void* g, void* l) {
    __builtin_amdgcn_global_load_lds(
        (const __attribute__((address_space(1))) unsigned int*)g,
        (__attribute__((address_space(3))) unsigned int*)l, 16, 0, 0);
}

#define FMA8(Cj, aj, b0, b1) \
    Cj[0] += (aj)*(b0).x; Cj[1] += (aj)*(b0).y; Cj[2] += (aj)*(b0).z; Cj[3] += (aj)*(b0).w; \
    Cj[4] += (aj)*(b1).x; Cj[5] += (aj)*(b1).y; Cj[6] += (aj)*(b1).z; Cj[7] += (aj)*(b1).w;

// ---------------- fused prep (W2b/b2b/W1b bf16 hi-lo split) + dst histogram ----------------
// BT2 chunk c in [0,65): c*8192 + half*4096 + o*64 + i   (shorts; half 0=hi,1=lo)
//   c<64: W2b[c, i*64+o]; c==64: b2b[i*64+o].  Rows are 128 B, no padding (global-read path).
// BT1 chunk c in [0,3):  [c*9216 + o*72 + k] hi, +4608 lo.  W1b[k, c*64+o]  (LDS path, padded)
__global__ void k_prep2(const float* __restrict__ W2b, const float* __restrict__ b2b,
                        const float* __restrict__ W1b, const int* __restrict__ ei,
                        short* __restrict__ BT2, short* __restrict__ BT1,
                        int* __restrict__ cnt) {
    int g = blockIdx.x * 256 + threadIdx.x;
    if (g < 262144) {
        float f = W2b[g];
        int o = g & 63, i = (g >> 6) & 63, k = g >> 12;
        unsigned short hi = bf16_rn(f);
        unsigned short lo = bf16_rn(f - bf16_to_f(hi));
        BT2[(size_t)k * 8192 + o * 64 + i]        = (short)hi;
        BT2[(size_t)k * 8192 + 4096 + o * 64 + i] = (short)lo;
    } else if (g < 266240) {
        int g2 = g - 262144;
        float f = b2b[g2];
        int o = g2 & 63, i = g2 >> 6;
        unsigned short hi = bf16_rn(f);
        unsigned short lo = bf16_rn(f - bf16_to_f(hi));
        BT2[(size_t)64 * 8192 + o * 64 + i]        = (short)hi;
        BT2[(size_t)64 * 8192 + 4096 + o * 64 + i] = (short)lo;
    } else if (g < 278528) {
        int g2 = g - 266240;
        float f = W1b[g2];
        int col = g2 % 192, k = g2 / 192;
        int c = col >> 6, o = col & 63;
        unsigned short hi = bf16_rn(f);
        unsigned short lo = bf16_rn(f - bf16_to_f(hi));
        BT1[c * 9216 + o * 72 + k]        = (short)hi;
        BT1[c * 9216 + 4608 + o * 72 + k] = (short)lo;
    } else {
        int e = g - 278528;       // < 65536
        atomicAdd(&cnt[ei[NE + e]], 1);
    }
}

// ---------------- exclusive scan over 32768 counts (single block) ----------------
__global__ __launch_bounds__(1024) void k_scan(const int* __restrict__ cnt,
                                               int* __restrict__ start,
                                               int* __restrict__ cursor) {
    __shared__ int wtot[16];
    const int t = threadIdx.x;
    const int lane = t & 63, wave = t >> 6;
    int local[32];
    const int base = t * 32;
    int s = 0;
    #pragma unroll
    for (int j = 0; j < 32; ++j) { local[j] = s; s += cnt[base + j]; }
    const int tot = s;
    int sc = tot;
    #pragma unroll
    for (int off = 1; off < 64; off <<= 1) {
        int v = __shfl_up(sc, off, 64);
        if (lane >= off) sc += v;
    }
    if (lane == 63) wtot[wave] = sc;
    __syncthreads();
    if (t == 0) {
        int run = 0;
        #pragma unroll
        for (int w = 0; w < 16; ++w) { int v = wtot[w]; wtot[w] = run; run += v; }
    }
    __syncthreads();
    const int tbase = wtot[wave] + (sc - tot);
    #pragma unroll
    for (int j = 0; j < 32; ++j) {
        int v = tbase + local[j];
        start[base + j] = v;
        cursor[base + j] = v;
    }
}

__global__ void k_fill(const int* __restrict__ ei, int* __restrict__ cursor,
                       int* __restrict__ perm) {
    int e = blockIdx.x * 256 + threadIdx.x;
    if (e < NE) {
        int d = ei[NE + e];
        int pos = atomicAdd(&cursor[d], 1);
        perm[pos] = e;
    }
}

// ---------------- layer-1 edge messages: MFMA, natural edge order ----------------
__global__ __launch_bounds__(256, 2) void k1_conv1(
    const float* __restrict__ x, const int* __restrict__ ei,
    const float* __restrict__ eatt,
    const float* __restrict__ W1a, const float* __restrict__ b1a,
    const short* __restrict__ BT1, const float* __restrict__ b1b,
    float* __restrict__ msg1)
{
    __shared__ __align__(16) short sBT1[3 * 9216];   // 55296 B
    __shared__ float sxs[128 * 4];
    __shared__ float sea[128 * 4];
    __shared__ float sW1a[192];
    __shared__ float sb1a[64];
    __shared__ float sb1b[192];

    const int tid = threadIdx.x;
    const int e0  = blockIdx.x * 128;
    const int wid = tid >> 6;
    const int lane = tid & 63;
    const int l15 = lane & 15, lhi = lane >> 4;

    // stage all 3 B-chunks async (54 KiB)
    {
        const char* src = (const char*)BT1;
        char* dst = (char*)&sBT1[0];
        for (int j = wid; j < 54; j += 4)
            gld16(src + j * 1024 + lane * 16, dst + j * 1024);
    }
    if (tid < 192) { sW1a[tid] = W1a[tid]; sb1b[tid] = b1b[tid]; }
    if (tid < 64)  sb1a[tid] = b1a[tid];
    if (tid < 128) {
        int e = e0 + tid;
        int s = ei[e];
        sxs[tid*4+0] = x[s*3+0];
        sxs[tid*4+1] = x[s*3+1];
        sxs[tid*4+2] = x[s*3+2];
        sea[tid*4+0] = eatt[e*3+0];
        sea[tid*4+1] = eatt[e*3+1];
        sea[tid*4+2] = eatt[e*3+2];
    }
    __syncthreads();

    bf16x8 ah[2][2], al[2][2];
    #pragma unroll
    for (int rt = 0; rt < 2; ++rt) {
        const int arow = wid*32 + rt*16 + l15;
        const float a0 = sea[arow*4+0], a1 = sea[arow*4+1], a2 = sea[arow*4+2];
        #pragma unroll
        for (int kc = 0; kc < 2; ++kc) {
            const int kb = kc*32 + lhi*8;
            bf16x8 H, L;
            #pragma unroll
            for (int j = 0; j < 8; ++j) {
                int k = kb + j;
                float f = fmaxf(sb1a[k] + a0*sW1a[k] + a1*sW1a[64+k] + a2*sW1a[128+k], 0.f);
                unsigned short hh = bf16_rn(f);
                unsigned short ll = bf16_rn(f - bf16_to_f(hh));
                H[j] = (short)hh; L[j] = (short)ll;
            }
            ah[rt][kc] = H; al[rt][kc] = L;
        }
    }
    float xr[2][4][3];
    #pragma unroll
    for (int rt = 0; rt < 2; ++rt)
        #pragma unroll
        for (int r = 0; r < 4; ++r) {
            int crow = wid*32 + rt*16 + lhi*4 + r;
            xr[rt][r][0] = sxs[crow*4+0];
            xr[rt][r][1] = sxs[crow*4+1];
            xr[rt][r][2] = sxs[crow*4+2];
        }

    f32x4 acc[2][4];
    #pragma unroll
    for (int rt = 0; rt < 2; ++rt)
        #pragma unroll
        for (int ot = 0; ot < 4; ++ot) { acc[rt][ot][0]=0.f; acc[rt][ot][1]=0.f; acc[rt][ot][2]=0.f; acc[rt][ot][3]=0.f; }

    #pragma unroll
    for (int c = 0; c < 3; ++c) {
        const short* Bh = &sBT1[c * 9216];
        const short* Bl = Bh + 4608;
        #pragma unroll
        for (int ot = 0; ot < 4; ++ot) {
            const int ob = (ot*16 + l15)*72 + lhi*8;
            bf16x8 bh0 = *(const bf16x8*)&Bh[ob];
            bf16x8 bh1 = *(const bf16x8*)&Bh[ob + 32];
            bf16x8 bl0 = *(const bf16x8*)&Bl[ob];
            bf16x8 bl1 = *(const bf16x8*)&Bl[ob + 32];
            #pragma unroll
            for (int rt = 0; rt < 2; ++rt) {
                f32x4 t = {0.f, 0.f, 0.f, 0.f};
                t = __builtin_amdgcn_mfma_f32_16x16x32_bf16(ah[rt][0], bh0, t, 0, 0, 0);
                t = __builtin_amdgcn_mfma_f32_16x16x32_bf16(al[rt][0], bh0, t, 0, 0, 0);
                t = __builtin_amdgcn_mfma_f32_16x16x32_bf16(ah[rt][0], bl0, t, 0, 0, 0);
                t = __builtin_amdgcn_mfma_f32_16x16x32_bf16(ah[rt][1], bh1, t, 0, 0, 0);
                t = __builtin_amdgcn_mfma_f32_16x16x32_bf16(al[rt][1], bh1, t, 0, 0, 0);
                t = __builtin_amdgcn_mfma_f32_16x16x32_bf16(ah[rt][1], bl1, t, 0, 0, 0);
                #pragma unroll
                for (int r = 0; r < 4; ++r)
                    acc[rt][ot][r] += xr[rt][r][c] * t[r];
            }
        }
    }
    #pragma unroll
    for (int rt = 0; rt < 2; ++rt) {
        #pragma unroll
        for (int ot = 0; ot < 4; ++ot) {
            const int o = ot*16 + l15;
            const float b0 = sb1b[o], b1 = sb1b[64+o], b2 = sb1b[128+o];
            #pragma unroll
            for (int r = 0; r < 4; ++r) {
                float v = acc[rt][ot][r] + xr[rt][r][0]*b0 + xr[rt][r][1]*b1 + xr[rt][r][2]*b2;
                int row = e0 + wid*32 + rt*16 + lhi*4 + r;
                msg1[(size_t)row * 64 + o] = v;
            }
        }
    }
}

// ---------------- layer-1 node update: segmented sum via perm gather ----------------
__global__ __launch_bounds__(256) void k2_node1(
    const float* __restrict__ msg1, const int* __restrict__ start,
    const int* __restrict__ cnt, const int* __restrict__ perm,
    const float* __restrict__ x, const float* __restrict__ root1,
    const float* __restrict__ bias1, float* __restrict__ h1)
{
    __shared__ float sR[192], sb[64];
    const int tid = threadIdx.x;
    if (tid < 192) sR[tid] = root1[tid];
    if (tid < 64)  sb[tid] = bias1[tid];
    __syncthreads();
    const int n = blockIdx.x * 64 + (tid >> 2);
    const int c = (tid & 3) * 16;
    const int st = start[n], num = cnt[n];
    float acc[16];
    #pragma unroll
    for (int l = 0; l < 16; ++l) acc[l] = 0.f;
    for (int d = 0; d < num; ++d) {
        const int row = perm[st + d];
        const float* rp = &msg1[(size_t)row * 64 + c];
        #pragma unroll
        for (int q = 0; q < 4; ++q) {
            float4 v = *(const float4*)(rp + q * 4);
            acc[q*4+0] += v.x; acc[q*4+1] += v.y; acc[q*4+2] += v.z; acc[q*4+3] += v.w;
        }
    }
    const float inv = 1.f / fmaxf((float)num, 1.f);
    const float x0 = x[n*3+0], x1 = x[n*3+1], x2 = x[n*3+2];
    float* hp = &h1[(size_t)n * 64 + c];
    #pragma unroll
    for (int q = 0; q < 4; ++q) {
        float4 ov;
        float* o4 = (float*)&ov;
        #pragma unroll
        for (int l = 0; l < 4; ++l) {
            int o = c + q*4 + l;
            float v = acc[q*4+l] * inv + sb[o] + x0*sR[o] + x1*sR[64+o] + x2*sR[128+o];
            o4[l] = elu_f(v);
        }
        *(float4*)(hp + q*4) = ov;
    }
}

// ---------------- layer-2 edge messages: MFMA, barrier-free k-loop ----------------
// msg2[e,o] = sum_k u[e,k]*( v[e,:]@Wk[:,o] ) + v[e,:]@b2b_mat[:,o]
// A = v = h1[src] (hi/lo frags, regs, built once). B read DIRECTLY from L2-resident BT2
// into registers, ping-pong 2-deep (load k+1 overlaps MFMA k). NO barriers in loop,
// NO LDS traffic in loop. u recomputed on VALU per chunk. 128 edges/block, 2 blocks/CU.
__global__ __launch_bounds__(256, 2) void k3_mfma(
    const float* __restrict__ h1, const int* __restrict__ ei,
    const float* __restrict__ eatt,
    const float* __restrict__ W2a, const float* __restrict__ b2a,
    const short* __restrict__ BT2,
    float* __restrict__ msg2)
{
    __shared__ __align__(16) float sV[128 * 68];     // 34816 B (prologue only)
    __shared__ float sea[128 * 4];
    __shared__ float sW2a[192];
    __shared__ float sb2a[64];

    const int tid = threadIdx.x;
    const int e0  = blockIdx.x * 128;
    const int wid = tid >> 6;
    const int lane = tid & 63;
    const int l15 = lane & 15, lhi = lane >> 4;

    if (tid < 192) sW2a[tid] = W2a[tid];
    if (tid < 64)  sb2a[tid] = b2a[tid];
    if (tid < 128) {
        int e = e0 + tid;
        sea[tid*4+0] = eatt[e*3+0];
        sea[tid*4+1] = eatt[e*3+1];
        sea[tid*4+2] = eatt[e*3+2];
    }
    // gather v rows (h1[src]) into sV
    {
        const int edge = tid >> 1, half = tid & 1;
        const int s = ei[e0 + edge];
        const float* row = h1 + (size_t)s * 64 + half * 32;
        float* dst = &sV[edge * 68 + half * 32];
        #pragma unroll
        for (int q = 0; q < 8; ++q)
            *(float4*)(dst + q*4) = *(const float4*)(row + q*4);
    }
    __syncthreads();

    // A-fragments (v) hi/lo, rows = wid*32+rt*16+l15, i = kc*32+lhi*8+j
    bf16x8 vh[2][2], vl[2][2];
    #pragma unroll
    for (int rt = 0; rt < 2; ++rt)
        #pragma unroll
        for (int kc = 0; kc < 2; ++kc) {
            const float* p = &sV[(wid*32 + rt*16 + l15)*68 + kc*32 + lhi*8];
            bf16x8 H, L;
            #pragma unroll
            for (int j = 0; j < 8; ++j) {
                float f = p[j];
                unsigned short hh = bf16_rn(f);
                unsigned short ll = bf16_rn(f - bf16_to_f(hh));
                H[j] = (short)hh; L[j] = (short)ll;
            }
            vh[rt][kc] = H; vl[rt][kc] = L;
        }
    // ea for C-rows (u-scale inputs)
    float er[2][4][3];
    #pragma unroll
    for (int rt = 0; rt < 2; ++rt)
        #pragma unroll
        for (int r = 0; r < 4; ++r) {
            int row = wid*32 + rt*16 + lhi*4 + r;
            er[rt][r][0] = sea[row*4+0];
            er[rt][r][1] = sea[row*4+1];
            er[rt][r][2] = sea[row*4+2];
        }

    f32x4 acc[2][4];
    #pragma unroll
    for (int rt = 0; rt < 2; ++rt)
        #pragma unroll
        for (int ot = 0; ot < 4; ++ot) { acc[rt][ot][0]=0.f; acc[rt][ot][1]=0.f; acc[rt][ot][2]=0.f; acc[rt][ot][3]=0.f; }

    // per-lane B byte offsets within a chunk (chunk = 8192 shorts = 16 KB; hi | lo at +4096)
    int boff[4];
    #pragma unroll
    for (int ot = 0; ot < 4; ++ot) boff[ot] = (ot*16 + l15)*64 + lhi*8;

    // load chunk k into frags[ot][{h0,h1,l0,l1}]
    #define LOADB(dst, kk)                                                        \
        {                                                                         \
            const short* p_ = BT2 + (size_t)(kk) * 8192;                          \
            _Pragma("unroll")                                                     \
            for (int ot = 0; ot < 4; ++ot) {                                      \
                dst[ot][0] = *(const bf16x8*)(p_ + boff[ot]);                     \
                dst[ot][1] = *(const bf16x8*)(p_ + boff[ot] + 32);                \
                dst[ot][2] = *(const bf16x8*)(p_ + boff[ot] + 4096);              \
                dst[ot][3] = *(const bf16x8*)(p_ + boff[ot] + 4096 + 32);         \
            }                                                                     \
        }

    // MFMA step on frags for chunk kk (kk==64 -> bias chunk, u=1)
    #define STEP(frag, kk)                                                        \
        {                                                                         \
            float us_[2][4];                                                      \
            if ((kk) < 64) {                                                      \
                const float wa = sW2a[(kk)], wb = sW2a[64+(kk)],                  \
                            wc = sW2a[128+(kk)], bb = sb2a[(kk)];                 \
                _Pragma("unroll")                                                 \
                for (int rt = 0; rt < 2; ++rt)                                    \
                    _Pragma("unroll")                                             \
                    for (int r = 0; r < 4; ++r)                                   \
                        us_[rt][r] = fmaxf(bb + er[rt][r][0]*wa +                 \
                                           er[rt][r][1]*wb + er[rt][r][2]*wc, 0.f);\
            } else {                                                              \
                _Pragma("unroll")                                                 \
                for (int rt = 0; rt < 2; ++rt)                                    \
                    _Pragma("unroll")                                             \
                    for (int r = 0; r < 4; ++r) us_[rt][r] = 1.f;                 \
            }                                                                     \
            _Pragma("unroll")                                                     \
            for (int ot = 0; ot < 4; ++ot) {                                      \
                _Pragma("unroll")                                                 \
                for (int rt = 0; rt < 2; ++rt) {                                  \
                    f32x4 t = {0.f, 0.f, 0.f, 0.f};                               \
                    t = __builtin_amdgcn_mfma_f32_16x16x32_bf16(vh[rt][0], frag[ot][0], t, 0, 0, 0); \
                    t = __builtin_amdgcn_mfma_f32_16x16x32_bf16(vl[rt][0], frag[ot][0], t, 0, 0, 0); \
                    t = __builtin_amdgcn_mfma_f32_16x16x32_bf16(vh[rt][0], frag[ot][2], t, 0, 0, 0); \
                    t = __builtin_amdgcn_mfma_f32_16x16x32_bf16(vh[rt][1], frag[ot][1], t, 0, 0, 0); \
                    t = __builtin_amdgcn_mfma_f32_16x16x32_bf16(vl[rt][1], frag[ot][1], t, 0, 0, 0); \
                    t = __builtin_amdgcn_mfma_f32_16x16x32_bf16(vh[rt][1], frag[ot][3], t, 0, 0, 0); \
                    _Pragma("unroll")                                             \
                    for (int r = 0; r < 4; ++r)                                   \
                        acc[rt][ot][r] += us_[rt][r] * t[r];                      \
                }                                                                 \
            }                                                                     \
        }

    bf16x8 ba[4][4], bb2[4][4];
    LOADB(ba, 0);
    // ping-pong: 65 chunks (0..64), pairs (k,k+1) for k=0,2,..,62, then 64 on ba
    for (int k = 0; k < 64; k += 2) {
        LOADB(bb2, k + 1);       // overlaps STEP(ba)
        STEP(ba, k);
        LOADB(ba, k + 2);        // k+2 <= 64 always; overlaps STEP(bb2)
        STEP(bb2, k + 1);
    }
    STEP(ba, 64);

    #undef LOADB
    #undef STEP

    // store (natural edge order): row = e0+wid*32+rt*16+lhi*4+r, col = ot*16+l15
    #pragma unroll
    for (int rt = 0; rt < 2; ++rt)
        #pragma unroll
        for (int ot = 0; ot < 4; ++ot) {
            const int o = ot*16 + l15;
            #pragma unroll
            for (int r = 0; r < 4; ++r) {
                int row = e0 + wid*32 + rt*16 + lhi*4 + r;
                msg2[(size_t)row * 64 + o] = acc[rt][ot][r];
            }
        }
}

// ---------------- layer-2 node update + FC, fused, perm-gather segmented sum ----------------
__global__ __launch_bounds__(256, 2) void k4_final(
    const float* __restrict__ msg2, const int* __restrict__ start,
    const int* __restrict__ cnt, const int* __restrict__ perm,
    const float* __restrict__ h1,
    const float* __restrict__ root2, const float* __restrict__ bias2,
    const float* __restrict__ Wf, const float* __restrict__ bf,
    float* __restrict__ out)
{
    __shared__ float sh1[32 * 65];
    __shared__ float sh2[32 * 65];
    __shared__ float sR[64 * 64];
    __shared__ float sW[64 * 128];
    __shared__ float sb2[64];
    __shared__ float sbf[128];
    __shared__ float sinv[32];
    __shared__ int   sstart[32];
    __shared__ int   scnt[32];
    const int tid = threadIdx.x;
    const int n0 = blockIdx.x * 32;

    for (int u = tid; u < 64*64/4; u += 256) ((float4*)sR)[u] = ((const float4*)root2)[u];
    for (int u = tid; u < 64*128/4; u += 256) ((float4*)sW)[u] = ((const float4*)Wf)[u];
    if (tid < 64)  sb2[tid] = bias2[tid];
    if (tid < 128) sbf[tid] = bf[tid];
    if (tid < 32) {
        int n = n0 + tid;
        int cc = cnt[n];
        sstart[tid] = start[n];
        scnt[tid] = cc;
        sinv[tid] = 1.f / fmaxf((float)cc, 1.f);
    }
    for (int u = tid; u < 32 * 16; u += 256) {
        int n = u >> 4, i4 = (u & 15) * 4;
        float4 v = *(const float4*)&h1[(size_t)(n0 + n) * 64 + i4];
        sh1[n*65+i4] = v.x; sh1[n*65+i4+1] = v.y; sh1[n*65+i4+2] = v.z; sh1[n*65+i4+3] = v.w;
    }
    __syncthreads();

    {
        const int tn = tid >> 4;
        const int o0 = (tid & 15) * 4;
        float acc[2][4];
        #pragma unroll
        for (int j = 0; j < 2; ++j) {
            int ln = tn * 2 + j;
            int st = sstart[ln], num = scnt[ln];
            float4 a = {0.f, 0.f, 0.f, 0.f};
            for (int d = 0; d < num; ++d) {
                int row = perm[st + d];
                float4 s = *(const float4*)&msg2[(size_t)row * 64 + o0];
                a.x += s.x; a.y += s.y; a.z += s.z; a.w += s.w;
            }
            float inv = sinv[ln];
            acc[j][0] = a.x*inv + sb2[o0+0];
            acc[j][1] = a.y*inv + sb2[o0+1];
            acc[j][2] = a.z*inv + sb2[o0+2];
            acc[j][3] = a.w*inv + sb2[o0+3];
        }
        #pragma unroll 8
        for (int k = 0; k < 64; ++k) {
            float4 r = *(const float4*)&sR[k*64 + o0];
            float h0 = sh1[(tn*2)*65 + k];
            float h1v = sh1[(tn*2+1)*65 + k];
            acc[0][0] += h0*r.x; acc[0][1] += h0*r.y; acc[0][2] += h0*r.z; acc[0][3] += h0*r.w;
            acc[1][0] += h1v*r.x; acc[1][1] += h1v*r.y; acc[1][2] += h1v*r.z; acc[1][3] += h1v*r.w;
        }
        #pragma unroll
        for (int j = 0; j < 2; ++j) {
            int n = tn * 2 + j;
            #pragma unroll
            for (int l = 0; l < 4; ++l) sh2[n*65 + o0 + l] = elu_f(acc[j][l]);
        }
    }
    __syncthreads();

    {
        const int tn = tid >> 4;
        const int c0 = (tid & 15) * 8;
        float acc[2][8];
        #pragma unroll
        for (int j = 0; j < 2; ++j)
            #pragma unroll
            for (int l = 0; l < 8; ++l) acc[j][l] = sbf[c0 + l];
        #pragma unroll 8
        for (int k = 0; k < 64; ++k) {
            float4 w0 = *(const float4*)&sW[k*128 + c0];
            float4 w1 = *(const float4*)&sW[k*128 + c0 + 4];
            float h0 = sh2[(tn*2)*65 + k];
            float h1v = sh2[(tn*2+1)*65 + k];
            FMA8(acc[0], h0, w0, w1);
            FMA8(acc[1], h1v, w0, w1);
        }
        #pragma unroll
        for (int j = 0; j < 2; ++j) {
            size_t n = n0 + tn * 2 + j;
            float4 oA, oB;
            oA.x = elu_f(acc[j][0]); oA.y = elu_f(acc[j][1]); oA.z = elu_f(acc[j][2]); oA.w = elu_f(acc[j][3]);
            oB.x = elu_f(acc[j][4]); oB.y = elu_f(acc[j][5]); oB.z = elu_f(acc[j][6]); oB.w = elu_f(acc[j][7]);
            *(float4*)&out[n*128 + c0]     = oA;
            *(float4*)&out[n*128 + c0 + 4] = oB;
        }
    }
}

extern "C" void kernel_launch(void* const* d_in, const int* in_sizes, int n_in,
                              void* d_out, int out_size, void* d_ws, size_t ws_size,
                              hipStream_t stream)
{
    const float* x     = (const float*)d_in[0];
    const int*   ei    = (const int*)d_in[1];
    const float* ea    = (const float*)d_in[2];
    const float* W1a   = (const float*)d_in[3];
    const float* b1a   = (const float*)d_in[4];
    const float* W1b   = (const float*)d_in[5];
    const float* b1b   = (const float*)d_in[6];
    const float* root1 = (const float*)d_in[7];
    const float* bias1 = (const float*)d_in[8];
    const float* W2a   = (const float*)d_in[9];
    const float* b2a   = (const float*)d_in[10];
    const float* W2b   = (const float*)d_in[11];
    const float* b2b   = (const float*)d_in[12];
    const float* root2 = (const float*)d_in[13];
    const float* bias2 = (const float*)d_in[14];
    const float* Wf    = (const float*)d_in[15];
    const float* bf    = (const float*)d_in[16];
    float* out = (float*)d_out;

    float* ws    = (float*)d_ws;
    float* msg1  = ws;                            // 4,194,304 f
    float* msg2  = ws + 4194304;                  // 4,194,304 f
    float* h1    = ws + 8388608;                  // 2,097,152 f
    short* BT2   = (short*)(ws + 10485760);       // 532,480 sh (fits old 599,040 slot)
    short* BT1   = (short*)(ws + 10785280);       // 27,648 sh
    int*   cnt_i = (int*)(ws + 10799104);         // NN
    int*   startp= (int*)(ws + 10831872);         // NN
    int*   cursor= (int*)(ws + 10864640);         // NN
    int*   perm  = (int*)(ws + 10897408);         // NE
    // total ws use ~41.9 MB

    hipMemsetAsync(cnt_i, 0, (size_t)NN * sizeof(int), stream);

    k_prep2 <<<1344,      256, 0, stream>>>(W2b, b2b, W1b, ei, BT2, BT1, cnt_i);
    k_scan  <<<1,        1024, 0, stream>>>(cnt_i, startp, cursor);
    k_fill  <<<NE/256,    256, 0, stream>>>(ei, cursor, perm);
    k1_conv1<<<NE/128,    256, 0, stream>>>(x, ei, ea, W1a, b1a, BT1, b1b, msg1);
    k2_node1<<<NN/64,     256, 0, stream>>>(msg1, startp, cnt_i, perm, x, root1, bias1, h1);
    k3_mfma <<<NE/128,    256, 0, stream>>>(h1, ei, ea, W2a, b2a, BT2, msg2);
    k4_final<<<NN/32,     256, 0, stream>>>(msg2, startp, cnt_i, perm, h1, root2, bias2, Wf, bf, out);
}